// Round 5
// baseline (281.057 us; speedup 1.0000x reference)
//
#include <hip/hip_runtime.h>
#include <hip/hip_bf16.h>

// Problem constants: B=4, S=4096, H=1024, NUM_LAYERS=20, EPS=1e-6
static constexpr int Mdim = 16384;   // B*S
static constexpr int Ndim = 1024;    // H (output 'o')
static constexpr int Kdim = 1024;    // H (contraction 'd')
static constexpr int NLAYERS = 20;
static constexpr int NT = Kdim / 64; // 16 K-tiles of BK=64
static constexpr int WSUM_BLOCKS = (Ndim * Kdim) / (256 * 4);  // 1024

typedef __bf16 bf16x8 __attribute__((ext_vector_type(8)));
typedef float f32x4 __attribute__((ext_vector_type(4)));

__device__ __forceinline__ ushort f2bf(float f) {
    unsigned u = __builtin_bit_cast(unsigned, f);
    u = (u + 0x7fffu + ((u >> 16) & 1u)) >> 16;   // RNE
    return (ushort)u;
}

__device__ __forceinline__ void gl_lds16(const ushort* g, ushort* l) {
    __builtin_amdgcn_global_load_lds((__attribute__((address_space(1))) void*)g,
                                     (__attribute__((address_space(3))) void*)l,
                                     16, 0, 0);
}

// ---------------------------------------------------------------------------
// Kernel 1 (merged): blocks [0, WSUM_BLOCKS) do the 20-layer w_sum -> bf16;
// blocks [WSUM_BLOCKS, +Mdim) do scaled-layerhack RMSNorm + bf16 X copy.
// wsum blocks are FIRST so wb is complete long before the rms tail finishes.
// ---------------------------------------------------------------------------
__global__ __launch_bounds__(256) void prep_kernel(const float* __restrict__ x,
                                                   const float* __restrict__ cw,
                                                   const float* __restrict__ wgt,
                                                   float* __restrict__ out,
                                                   ushort* __restrict__ xb,
                                                   ushort* __restrict__ wb) {
    const int t = threadIdx.x;
    if (blockIdx.x < WSUM_BLOCKS) {
        size_t e = ((size_t)blockIdx.x * 256 + t) * 4;
        float4 acc = make_float4(0.f, 0.f, 0.f, 0.f);
        for (int l = 0; l < NLAYERS; ++l) {
            float4 v = *(const float4*)&cw[(size_t)l * (Ndim * Kdim) + e];
            acc.x += v.x; acc.y += v.y; acc.z += v.z; acc.w += v.w;
        }
        const float sc = 1.0f / (float)NLAYERS;
        ushort4 o;
        o.x = f2bf(acc.x * sc); o.y = f2bf(acc.y * sc);
        o.z = f2bf(acc.z * sc); o.w = f2bf(acc.w * sc);
        *(ushort4*)&wb[e] = o;
        return;
    }
    const size_t row = blockIdx.x - WSUM_BLOCKS;
    const float* xr = x + row * 1024;
    float4 v = *(const float4*)&xr[t * 4];

    float mx = fmaxf(fmaxf(fabsf(v.x), fabsf(v.y)), fmaxf(fabsf(v.z), fabsf(v.w)));
    float ss = v.x * v.x + v.y * v.y + v.z * v.z + v.w * v.w;
    #pragma unroll
    for (int off = 1; off < 64; off <<= 1) {
        mx = fmaxf(mx, __shfl_xor(mx, off));
        ss += __shfl_xor(ss, off);
    }
    __shared__ float sm[4], sv[4];
    const int w = t >> 6, l = t & 63;
    if (l == 0) { sm[w] = mx; sv[w] = ss; }
    __syncthreads();
    mx = fmaxf(fmaxf(sm[0], sm[1]), fmaxf(sm[2], sm[3]));
    ss = sv[0] + sv[1] + sv[2] + sv[3];

    mx = fmaxf(mx, 1e-6f);                       // clip
    float var = ss / (mx * mx * 1024.0f);        // mean(concat(x,-x)) == 0 exactly
    float s = rsqrtf(var + 1e-6f) / mx;

    float4 wv = *(const float4*)&wgt[t * 4];
    float4 o;
    o.x = v.x * s * wv.x; o.y = v.y * s * wv.y;
    o.z = v.z * s * wv.z; o.w = v.w * s * wv.w;
    *(float4*)&out[row * 1024 + t * 4] = o;

    ushort4 ub;
    ub.x = f2bf(v.x); ub.y = f2bf(v.y); ub.z = f2bf(v.z); ub.w = f2bf(v.w);
    *(ushort4*)&xb[row * 1024 + t * 4] = ub;
}

// ---------------------------------------------------------------------------
// Kernel 2: bf16 GEMM, 256x256 tile, BK=64, 8-phase schedule (m201 template).
//   C[m][n] = sum_d X[m][d] * W[n][d], f32 out.
//   8 waves (2M x 4N), per-wave out 128x64. LDS 128KiB = 2 buf x (A 32K + B 32K).
//   OPERAND-SWAPPED MFMA: mfma(b, a) so each lane's 4 acc regs are 4
//   consecutive n at fixed m -> dwordx4 epilogue stores.
// ---------------------------------------------------------------------------
__global__ __launch_bounds__(512, 2) void gemm8_kernel(const ushort* __restrict__ X,
                                                       const ushort* __restrict__ W,
                                                       float* __restrict__ C) {
    __shared__ __attribute__((aligned(16))) ushort lds[65536];  // 128 KiB
    const char* ldsc = (const char*)lds;

    const int tid = threadIdx.x;
    const int w = tid >> 6, l = tid & 63;
    const int wm = w >> 2, wn = w & 3;

    // XCD-chunked swizzle: 256 blocks, 8 XCDs, 32 blocks/XCD.
    const int bid = blockIdx.x;
    const int swz = (bid & 7) * 32 + (bid >> 3);
    const int m0 = (swz >> 2) * 256;
    const int n0 = (swz & 3) * 256;

    // staging: thread covers 16B; 512 thr = 64 rows x 128B per gl_lds issue
    const int srow = tid >> 3;
    const int scol = 8 * ((tid & 7) ^ (srow & 7));     // inverse-swizzled source col
    const ushort* gA = X + (size_t)(m0 + srow) * Kdim + scol;
    const ushort* gB = W + (size_t)(n0 + srow) * Kdim + scol;

    // half-tile j: jt=j>>2 (K-tile), r=j&3 (0:A0,1:A1,2:B0,3:B1), buf=jt&1
    auto STAGE = [&](int j) {
        if (j >= 4 * NT) return;
        const int jt = j >> 2, r = j & 3;
        const ushort* src = ((r & 2) ? gB : gA) + (size_t)(r & 1) * (128 * Kdim) + jt * 64;
        ushort* dst = lds + (jt & 1) * 32768 + r * 8192 + tid * 8;
        gl_lds16(src, dst);
        gl_lds16(src + 64 * Kdim, dst + 4096);
    };

    // per-lane fragment read bases (bytes, swizzled): row stride 128B,
    // byte ^= (row&7)<<4; ks=1 fragment = base ^ 64.
    const int swzl = (l & 7) << 4;
    const int colp = ((l >> 4) * 16) ^ swzl;
    const int abase = wm * 16384 + (l & 15) * 128 + colp;
    const int bbase = 32768 + (wn >> 1) * 16384 + ((wn & 1) * 64 + (l & 15)) * 128 + colp;

    f32x4 acc[8][4] = {};
    bf16x8 a0[4][2], a1[4][2], bfr[2][2];

    // prologue: tile0 (4 half-tiles) + 3 half-tiles of tile1, single wait
    STAGE(0); STAGE(1); STAGE(2); STAGE(3);
    STAGE(4); STAGE(5); STAGE(6);
    asm volatile("s_waitcnt vmcnt(6)" ::: "memory");   // tile0 fully landed
    __builtin_amdgcn_s_barrier();

#define LOAD_A(aset, mh_)                                                    \
    _Pragma("unroll") for (int mf = 0; mf < 4; ++mf) {                       \
        const int ad = bufb + abase + (mh_) * 8192 + mf * 2048;              \
        aset[mf][0] = *(const bf16x8*)(ldsc + ad);                           \
        aset[mf][1] = *(const bf16x8*)(ldsc + (ad ^ 64));                    \
    }
#define LOAD_B(nh_)                                                          \
    _Pragma("unroll") for (int nf = 0; nf < 2; ++nf) {                       \
        const int bd = bufb + bbase + (nh_) * 4096 + nf * 2048;              \
        bfr[nf][0] = *(const bf16x8*)(ldsc + bd);                            \
        bfr[nf][1] = *(const bf16x8*)(ldsc + (bd ^ 64));                     \
    }
// operand-swapped: mfma(B, A) -> D[row=(l>>4)*4+reg -> n][col=l&15 -> m]
#define MFMA_Q(aset, mh_, nh_)                                               \
    __builtin_amdgcn_s_setprio(1);                                           \
    _Pragma("unroll") for (int mf = 0; mf < 4; ++mf)                         \
        _Pragma("unroll") for (int nf = 0; nf < 2; ++nf) {                   \
            acc[(mh_) * 4 + mf][(nh_) * 2 + nf] =                            \
                __builtin_amdgcn_mfma_f32_16x16x32_bf16(bfr[nf][0], aset[mf][0], \
                    acc[(mh_) * 4 + mf][(nh_) * 2 + nf], 0, 0, 0);           \
            acc[(mh_) * 4 + mf][(nh_) * 2 + nf] =                            \
                __builtin_amdgcn_mfma_f32_16x16x32_bf16(bfr[nf][1], aset[mf][1], \
                    acc[(mh_) * 4 + mf][(nh_) * 2 + nf], 0, 0, 0);           \
        }                                                                    \
    __builtin_amdgcn_s_setprio(0);

    #pragma unroll 2
    for (int kt = 0; kt < NT; ++kt) {
        const int bufb = (kt & 1) * 65536;
        // phase 0: quadrant (0,0) — reads A0,B0; issues next-buf B1
        LOAD_A(a0, 0);
        LOAD_B(0);
        STAGE(4 * kt + 7);
        __builtin_amdgcn_s_barrier();
        MFMA_Q(a0, 0, 0);
        __builtin_amdgcn_s_barrier();
        // phase 1: quadrant (1,0) — reads A1; next-buf A0 overwrite is 1 tile out
        LOAD_A(a1, 1);
        STAGE(4 * kt + 8);
        __builtin_amdgcn_s_barrier();
        MFMA_Q(a1, 1, 0);
        __builtin_amdgcn_s_barrier();
        // phase 2: quadrant (0,1) — reads B1
        LOAD_B(1);
        STAGE(4 * kt + 9);
        __builtin_amdgcn_s_barrier();
        MFMA_Q(a0, 0, 1);
        __builtin_amdgcn_s_barrier();
        // phase 3: quadrant (1,1); tile boundary: next tile must be landed,
        // keep 3 half-tiles (6 loads) in flight
        STAGE(4 * kt + 10);
        if (kt < NT - 2) asm volatile("s_waitcnt vmcnt(6)" ::: "memory");
        else             asm volatile("s_waitcnt vmcnt(0)" ::: "memory");
        __builtin_amdgcn_s_barrier();
        MFMA_Q(a1, 1, 1);
        __builtin_amdgcn_s_barrier();
    }
#undef LOAD_A
#undef LOAD_B
#undef MFMA_Q

    // epilogue: lane holds 4 consecutive n at fixed m -> dwordx4 stores
    const int crow0 = m0 + wm * 128 + (l & 15);
    const int ccol0 = n0 + wn * 64 + (l >> 4) * 4;
    #pragma unroll
    for (int mh = 0; mh < 2; ++mh)
        #pragma unroll
        for (int mf = 0; mf < 4; ++mf)
            #pragma unroll
            for (int nh = 0; nh < 2; ++nh)
                #pragma unroll
                for (int nf = 0; nf < 2; ++nf) {
                    size_t base = (size_t)(crow0 + mh * 64 + mf * 16) * Ndim
                                + (ccol0 + nh * 32 + nf * 16);
                    *(f32x4*)&C[base] = acc[mh * 4 + mf][nh * 2 + nf];
                }
}

extern "C" void kernel_launch(void* const* d_in, const int* in_sizes, int n_in,
                              void* d_out, int out_size, void* d_ws, size_t ws_size,
                              hipStream_t stream) {
    const float* x  = (const float*)d_in[0];   // (4,4096,1024) f32
    const float* cw = (const float*)d_in[1];   // (20,1024,1024) f32
    const float* nw = (const float*)d_in[2];   // (1024,) f32

    float* rms_out  = (float*)d_out;                       // 16777216 f32
    float* conv_out = rms_out + (size_t)Mdim * Ndim;       // next 16777216 f32

    ushort* xb = (ushort*)d_ws;                            // 32 MB bf16 X
    ushort* wb = xb + (size_t)Mdim * Kdim;                 // 2 MB bf16 W_sum/20

    hipLaunchKernelGGL(prep_kernel, dim3(WSUM_BLOCKS + Mdim), dim3(256), 0, stream,
                       x, cw, nw, rms_out, xb, wb);
    hipLaunchKernelGGL(gemm8_kernel, dim3(256), dim3(512), 0, stream,
                       xb, wb, conv_out);
}